// Round 8
// baseline (1160.612 us; speedup 1.0000x reference)
//
#include <hip/hip_runtime.h>
#include <hip/hip_bf16.h>

// GraphUpsampler: N=4096 -> M=8192 dense GCN, 3 iters, out = sigmoid(Xu@Xu.T) f32 [8192,8192].
// R8: fp8-e4m3 Adj / Z / W_up + fp8 MFMA aggregation + bf16 split-K partials.
//     Cuts total HBM traffic 2.34 GB -> ~1.45 GB. Adj stage-tiled-64 for fp8:
//     addr(i,k) = ((i>>6)*KC + (k>>6))*4096 + (i&63)*64 + (k&63), stage = 4KB.

#define N_NODES 4096
#define M_NODES 8192
#define DIM 128
#define SLICE_ELEMS ((size_t)M_NODES * DIM)   // elements per bf16 partial slice

typedef __attribute__((ext_vector_type(4))) float f32x4;
typedef __attribute__((ext_vector_type(8))) short bf16x8;

__device__ __forceinline__ unsigned short f2bf(float f) {
  union { float f; unsigned u; } v; v.f = f;
  unsigned r = v.u + 0x7fffu + ((v.u >> 16) & 1u);
  return (unsigned short)(r >> 16);
}
__device__ __forceinline__ float bf2f(unsigned short b) {
  union { unsigned u; float f; } v; v.u = ((unsigned)b) << 16;
  return v.f;
}
__device__ __forceinline__ unsigned char f2fp8(float a) {
  return (unsigned char)(__builtin_amdgcn_cvt_pk_fp8_f32(a, a, 0, false) & 0xff);
}
__device__ __forceinline__ unsigned f2fp8x4(float a, float b, float c, float d) {
  int p = __builtin_amdgcn_cvt_pk_fp8_f32(a, b, 0, false);
  p = __builtin_amdgcn_cvt_pk_fp8_f32(c, d, p, true);
  return (unsigned)p;
}

__device__ __forceinline__ void gld16(void* lds, const void* g) {
  __builtin_amdgcn_global_load_lds(
      (const __attribute__((address_space(1))) unsigned int*)g,
      (__attribute__((address_space(3))) unsigned int*)lds, 16, 0, 0);
}

__device__ __forceinline__ float sigmoidf_(float x) { return 1.0f / (1.0f + __expf(-x)); }

// ---------------- cast / init kernels ----------------

__global__ void cast_x_kernel(const float* __restrict__ X, unsigned short* __restrict__ Xu,
                              unsigned char* __restrict__ XT) {
  int idx = blockIdx.x * 256 + threadIdx.x;          // N*DIM
  int i = idx >> 7, c = idx & 127;
  float v = X[idx];
  Xu[idx] = f2bf(v);
  XT[(size_t)c * N_NODES + i] = f2fp8(v);            // X^T fp8 [128][4096]
}

// W_up f32 -> fp8 stage-tiled-64 (KC=64)
__global__ void cast_wup_kernel(const float4* __restrict__ W, unsigned char* __restrict__ Wb) {
  int idx4 = blockIdx.x * 256 + threadIdx.x;         // N*N/4
  int r = idx4 >> 10, c = (idx4 & 1023) << 2;
  float4 v = W[idx4];
  unsigned p = f2fp8x4(v.x, v.y, v.z, v.w);
  *(unsigned*)&Wb[((size_t)(r >> 6) * 64 + (c >> 6)) * 4096 + (r & 63) * 64 + (c & 63)] = p;
}

__global__ void cast_wt_kernel(const float* __restrict__ W, unsigned short* __restrict__ WT) {
  int idx = blockIdx.x * 256 + threadIdx.x;          // 128*128
  int k = idx >> 7, c = idx & 127;
  WT[c * DIM + k] = f2bf(W[idx]);                    // W^T bf16 [out][in]
}

// A f32 -> 3 fp8 quadrants of stage-tiled-64 Adj (KC=128), A symmetric; + colsum(A)
__global__ void cast_a_kernel(const float* __restrict__ A, unsigned char* __restrict__ Adj,
                              float* __restrict__ colsumA) {
  int c = blockIdx.x * 256 + threadIdx.x;            // 0..4095
  int r0 = blockIdx.y * 128;
  size_t cb = (size_t)(c >> 6) * 4096 + (c & 63);
  float s = 0.f;
  for (int r = 0; r < 128; ++r) {
    int i = r0 + r;
    float a = A[(size_t)i * N_NODES + c];
    unsigned char b = f2fp8(a);
    size_t rt = (size_t)(i >> 6) * 128 * 4096 + (size_t)(i & 63) * 64;
    Adj[rt + cb] = b;                                   // (i, c)
    Adj[rt + cb + (size_t)64 * 4096] = b;               // (i, 4096+c)
    Adj[rt + (size_t)64 * 128 * 4096 + cb] = b;         // (4096+i, c)
    s += a;
  }
  atomicAdd(&colsumA[c], s);
}

__global__ void init_deg_kernel(const float* __restrict__ colsumA, float* __restrict__ deg) {
  int i = blockIdx.x * 256 + threadIdx.x;            // 8192
  deg[i] = (i < N_NODES) ? 2.0f * colsumA[i] : colsumA[i - N_NODES];
}

// ---------------- fp8 LDS-staged split-K aggregation, 64-row tiles ----------------
// C_partial[by] = At(fp8 stage-tiled)[64 rows bx] @ B (fp8 BT[128 n][ldb k]); K-stage = 64.

__global__ __launch_bounds__(256)
void agg_kernel(const unsigned char* __restrict__ At, int kcTotal,
                const unsigned char* __restrict__ BT, long ldb,
                unsigned short* __restrict__ accBase, int kIters) {
  __shared__ __align__(16) unsigned char lA[4096];   // [64 r][64 k]
  __shared__ __align__(16) unsigned char lB[8192];   // [128 n][64 k]
  const int t = threadIdx.x, w = t >> 6, lane = t & 63;
  const int q = lane >> 4, l15 = lane & 15;
  const size_t abase = ((size_t)blockIdx.x * kcTotal + (size_t)blockIdx.y * kIters) * 4096;
  const size_t bk = (size_t)blockIdx.y * kIters * 64;
  const int brow = t >> 2, bchk = t & 3;

  f32x4 acc[8];
#pragma unroll
  for (int b = 0; b < 8; ++b) acc[b] = (f32x4)0.f;

  for (int s = 0; s < kIters; ++s) {
    __syncthreads();
    gld16(&lA[t * 16], &At[abase + (size_t)s * 4096 + t * 16]);
    gld16(&lB[t * 16], &BT[(size_t)brow * ldb + bk + s * 64 + bchk * 16]);
    gld16(&lB[4096 + t * 16], &BT[(size_t)(64 + brow) * ldb + bk + s * 64 + bchk * 16]);
    __syncthreads();
    long long a0 = *(const long long*)&lA[(w * 16 + l15) * 64 + q * 8];
    long long a1 = *(const long long*)&lA[(w * 16 + l15) * 64 + 32 + q * 8];
#pragma unroll
    for (int nt = 0; nt < 8; ++nt) {
      long long b0 = *(const long long*)&lB[(nt * 16 + l15) * 64 + q * 8];
      long long b1 = *(const long long*)&lB[(nt * 16 + l15) * 64 + 32 + q * 8];
      acc[nt] = __builtin_amdgcn_mfma_f32_16x16x32_fp8_fp8(a0, b0, acc[nt], 0, 0, 0);
      acc[nt] = __builtin_amdgcn_mfma_f32_16x16x32_fp8_fp8(a1, b1, acc[nt], 0, 0, 0);
    }
  }
  // packed bf16 partial: 8B/lane coalesced
  unsigned short* ct = accBase + (size_t)blockIdx.y * SLICE_ELEMS + (size_t)blockIdx.x * 8192;
#pragma unroll
  for (int nt = 0; nt < 8; ++nt) {
    ushort4 o;
    o.x = f2bf(acc[nt][0]); o.y = f2bf(acc[nt][1]);
    o.z = f2bf(acc[nt][2]); o.w = f2bf(acc[nt][3]);
    *(ushort4*)&ct[(w * 8 + nt) * 256 + (q * 16 + l15) * 4] = o;
  }
}

// sum packed bf16 partials + epilogue -> bf16 row-major Xu
// mode 0: v = s + bias_row[row];  mode 1: v = relu(rsqrt(deg[row])*s + bias_col[col])
__global__ void reduce_acc_kernel(const unsigned short* __restrict__ acc,
                                  unsigned short* __restrict__ dst,
                                  const float* __restrict__ bias_row,
                                  const float* __restrict__ bias_col,
                                  const float* __restrict__ deg, int mode, int nSlices) {
  int p = blockIdx.x * 256 + threadIdx.x;
  float s = 0.f;
  for (int sp = 0; sp < nSlices; ++sp) s += bf2f(acc[(size_t)sp * SLICE_ELEMS + p]);
  int tile = p >> 13, r = p & 8191;
  int grp = r >> 8, r2 = r & 255;
  int w = grp >> 3, nt = grp & 7;
  int i = r2 & 3, ql = r2 >> 2;
  int row = tile * 64 + w * 16 + (ql >> 4) * 4 + i;
  int col = nt * 16 + (ql & 15);
  float v;
  if (mode == 0) v = s + bias_row[row];
  else {
    float d = deg[row];
    float dv = d > 0.f ? rsqrtf(d) : 0.f;
    v = fmaxf(dv * s + bias_col[col], 0.f);
  }
  dst[(size_t)row * DIM + col] = f2bf(v);
}

// ---------------- rebuild: out = sigmoid(XA @ XB^T), K=128, bf16 MFMA ----------------
// MODE 0: fp8 stage-tiled-64 out (KC=128) + fused col-sums into deg.
// MODE 1: f32 row-major out (final), repacked via LDS for f32x4 row stores.

template <int MODE>
__global__ __launch_bounds__(256)
void rebuild_kernel(const unsigned short* __restrict__ XA,
                    const unsigned short* __restrict__ XB,
                    void* __restrict__ out, long p1 /*MODE0:row0, MODE1:ldo*/,
                    long col0, float* __restrict__ deg) {
  __shared__ __align__(16) unsigned char smem[32768];
  __shared__ float lcol[128];
  unsigned short* lA = (unsigned short*)smem;
  unsigned short* lB = (unsigned short*)(smem + 16384);
  const int t = threadIdx.x, w = t >> 6, lane = t & 63;
  const int q = lane >> 4, l15 = lane & 15;
  const int i0 = blockIdx.x * 128, j0 = blockIdx.y * 128;
  const int srow = t >> 2, schk = t & 3;
#pragma unroll
  for (int kk = 0; kk < 4; ++kk)
#pragma unroll
    for (int h = 0; h < 2; ++h) {
      gld16(&lA[kk * 4096 + h * 2048 + t * 8],
            &XA[(size_t)(i0 + h * 64 + srow) * DIM + kk * 32 + schk * 8]);
      gld16(&lB[kk * 4096 + h * 2048 + t * 8],
            &XB[(size_t)(j0 + h * 64 + srow) * DIM + kk * 32 + schk * 8]);
    }
  if (MODE == 0 && t < 128) lcol[t] = 0.f;
  __syncthreads();

  f32x4 acc[2][8];
#pragma unroll
  for (int a = 0; a < 2; ++a)
#pragma unroll
    for (int b = 0; b < 8; ++b) acc[a][b] = (f32x4)0.f;

#pragma unroll
  for (int kk = 0; kk < 4; ++kk) {
    bf16x8 a0 = *(const bf16x8*)&lA[kk * 4096 + (w * 32 + l15) * 32 + q * 8];
    bf16x8 a1 = *(const bf16x8*)&lA[kk * 4096 + (w * 32 + 16 + l15) * 32 + q * 8];
#pragma unroll
    for (int nt = 0; nt < 8; ++nt) {
      bf16x8 b = *(const bf16x8*)&lB[kk * 4096 + (nt * 16 + l15) * 32 + q * 8];
      acc[0][nt] = __builtin_amdgcn_mfma_f32_16x16x32_bf16(a0, b, acc[0][nt], 0, 0, 0);
      acc[1][nt] = __builtin_amdgcn_mfma_f32_16x16x32_bf16(a1, b, acc[1][nt], 0, 0, 0);
    }
  }
  __syncthreads();   // staging reads done; smem reusable

  if (MODE == 0) {
    unsigned char* lC = smem;   // [128][136] fp8 bytes
#pragma unroll
    for (int mt = 0; mt < 2; ++mt)
#pragma unroll
      for (int nt = 0; nt < 8; ++nt) {
        float cs = 0.f;
#pragma unroll
        for (int i = 0; i < 4; ++i) {
          float sv = sigmoidf_(acc[mt][nt][i]);
          cs += sv;
          lC[(w * 32 + mt * 16 + q * 4 + i) * 136 + nt * 16 + l15] = f2fp8(sv);
        }
        cs += __shfl_xor(cs, 16);
        cs += __shfl_xor(cs, 32);
        if (lane < 16) atomicAdd(&lcol[nt * 16 + lane], cs);
      }
    __syncthreads();
    // fp8 stage-tiled-64 store: 8B chunks
    unsigned char* og = (unsigned char*)out;
    const long rowbase = p1 + i0, colbase = col0 + j0;
    const size_t tb = ((size_t)(rowbase >> 6) * 128 + (colbase >> 6)) * 4096;
#pragma unroll
    for (int cc = 0; cc < 8; ++cc) {
      int ch = t + cc * 256;                     // 0..2047
      int row = ch >> 4, c8 = (ch & 15) * 8;
      *(long long*)&og[tb + (size_t)(row >> 6) * 128 * 4096 + (size_t)(c8 >> 6) * 4096 +
                       (row & 63) * 64 + (c8 & 63)] =
          *(const long long*)&lC[row * 136 + c8];
    }
    if (t < 128) atomicAdd(&deg[colbase + t], lcol[t]);
  } else {
    float* og = (float*)out;
    float* lCf = (float*)smem;                   // [64][128] f32
#pragma unroll
    for (int h2 = 0; h2 < 2; ++h2) {
      __syncthreads();
      if ((w >> 1) == h2) {
#pragma unroll
        for (int mt = 0; mt < 2; ++mt)
#pragma unroll
          for (int nt = 0; nt < 8; ++nt)
#pragma unroll
            for (int i = 0; i < 4; ++i)
              lCf[((w & 1) * 32 + mt * 16 + q * 4 + i) * 128 + nt * 16 + l15] =
                  sigmoidf_(acc[mt][nt][i]);
      }
      __syncthreads();
#pragma unroll
      for (int j = 0; j < 8; ++j) {
        int ch = t + j * 256;
        int r64 = ch >> 5, c4 = (ch & 31) * 4;
        *(f32x4*)&og[(size_t)(i0 + h2 * 64 + r64) * p1 + j0 + c4] =
            *(const f32x4*)&lCf[r64 * 128 + c4];
      }
    }
  }
}

// ---------------- Z^T = (rsqrt(deg) ⊙ (Xu @ W)) transposed -> fp8 [128][8192] ----------------

__global__ __launch_bounds__(256)
void yz_kernel(const unsigned short* __restrict__ Xu, const unsigned short* __restrict__ WT,
               const float* __restrict__ deg, unsigned char* __restrict__ ZT, long ldz) {
  __shared__ __align__(16) unsigned char smem[32768];
  unsigned short* lA = (unsigned short*)smem;
  unsigned short* lB = (unsigned short*)(smem + 16384);
  const int t = threadIdx.x, w = t >> 6, lane = t & 63;
  const int q = lane >> 4, l15 = lane & 15;
  const int r0 = blockIdx.x * 128;
  const int srow = t >> 2, schk = t & 3;
#pragma unroll
  for (int kk = 0; kk < 4; ++kk)
#pragma unroll
    for (int h = 0; h < 2; ++h) {
      gld16(&lA[kk * 4096 + h * 2048 + t * 8],
            &Xu[(size_t)(r0 + h * 64 + srow) * DIM + kk * 32 + schk * 8]);
      gld16(&lB[kk * 4096 + h * 2048 + t * 8],
            &WT[(size_t)(h * 64 + srow) * DIM + kk * 32 + schk * 8]);
    }
  __syncthreads();

  f32x4 acc[2][8];
#pragma unroll
  for (int a = 0; a < 2; ++a)
#pragma unroll
    for (int b = 0; b < 8; ++b) acc[a][b] = (f32x4)0.f;

#pragma unroll
  for (int kk = 0; kk < 4; ++kk) {
    bf16x8 a0 = *(const bf16x8*)&lA[kk * 4096 + (w * 32 + l15) * 32 + q * 8];
    bf16x8 a1 = *(const bf16x8*)&lA[kk * 4096 + (w * 32 + 16 + l15) * 32 + q * 8];
#pragma unroll
    for (int nt = 0; nt < 8; ++nt) {
      bf16x8 b = *(const bf16x8*)&lB[kk * 4096 + (nt * 16 + l15) * 32 + q * 8];
      acc[0][nt] = __builtin_amdgcn_mfma_f32_16x16x32_bf16(a0, b, acc[0][nt], 0, 0, 0);
      acc[1][nt] = __builtin_amdgcn_mfma_f32_16x16x32_bf16(a1, b, acc[1][nt], 0, 0, 0);
    }
  }
  float dv[2][4];
#pragma unroll
  for (int mt = 0; mt < 2; ++mt)
#pragma unroll
    for (int i = 0; i < 4; ++i) {
      float d = deg[r0 + w * 32 + mt * 16 + q * 4 + i];
      dv[mt][i] = d > 0.f ? rsqrtf(d) : 0.f;
    }
  __syncthreads();
  unsigned char* lT = smem;   // [c 128][r 136] fp8
#pragma unroll
  for (int mt = 0; mt < 2; ++mt)
#pragma unroll
    for (int nt = 0; nt < 8; ++nt)
#pragma unroll
      for (int i = 0; i < 4; ++i) {
        int r = w * 32 + mt * 16 + q * 4 + i;
        lT[(nt * 16 + l15) * 136 + r] = f2fp8(dv[mt][i] * acc[mt][nt][i]);
      }
  __syncthreads();
#pragma unroll
  for (int cc = 0; cc < 8; ++cc) {
    int ch = t + cc * 256;
    int c = ch >> 4, r8 = (ch & 15) * 8;
    *(long long*)&ZT[(size_t)c * ldz + r0 + r8] = *(const long long*)&lT[c * 136 + r8];
  }
}

// ---------------- driver ----------------

extern "C" void kernel_launch(void* const* d_in, const int* in_sizes, int n_in,
                              void* d_out, int out_size, void* d_ws, size_t ws_size,
                              hipStream_t stream) {
  (void)in_sizes; (void)n_in; (void)out_size;
  const float* X   = (const float*)d_in[0];
  const float* A   = (const float*)d_in[1];
  const float* Wup = (const float*)d_in[2];
  const float* bup = (const float*)d_in[3];
  const float* W1  = (const float*)d_in[4];
  const float* b1  = (const float*)d_in[5];
  const float* W2  = (const float*)d_in[6];
  const float* b2  = (const float*)d_in[7];

  const size_t ADJ_BYTES = (size_t)M_NODES * M_NODES;   // fp8: 67 MB
  char* ws = (char*)d_ws;
  size_t off = 0;
  auto alloc = [&](size_t bytes) {
    char* p = ws + off;
    off += (bytes + 255) & ~(size_t)255;
    return p;
  };
  unsigned short* accb    = (unsigned short*)alloc(8 * SLICE_ELEMS * 2);   // 16.7 MB bf16
  unsigned short* Xu      = (unsigned short*)alloc((size_t)M_NODES * DIM * 2);
  unsigned char*  ZT      = (unsigned char*)alloc((size_t)DIM * M_NODES);
  unsigned char*  XT      = (unsigned char*)alloc((size_t)DIM * N_NODES);
  unsigned short* W1T     = (unsigned short*)alloc(DIM * DIM * 2);
  unsigned short* W2T     = (unsigned short*)alloc(DIM * DIM * 2);
  float*          colsumA = (float*)alloc(N_NODES * 4);
  float*          deg     = (float*)alloc(M_NODES * 4);

  unsigned char* Adj;
  if (ws_size >= off + ADJ_BYTES) Adj = (unsigned char*)(ws + off);
  else                            Adj = (unsigned char*)d_out;  // Adj dead before final write
  unsigned char* Wupb = Adj;   // fp8 W_up aliases Adj (consumed before Adj written)

  unsigned short* XuNew = Xu + (size_t)N_NODES * DIM;

  hipMemsetAsync(colsumA, 0, N_NODES * 4, stream);
  cast_x_kernel<<<N_NODES * DIM / 256, 256, 0, stream>>>(X, Xu, XT);
  cast_wup_kernel<<<((size_t)N_NODES * N_NODES / 4) / 256, 256, 0, stream>>>(
      (const float4*)Wup, Wupb);
  cast_wt_kernel<<<64, 256, 0, stream>>>(W1, W1T);
  cast_wt_kernel<<<64, 256, 0, stream>>>(W2, W2T);

  // new = W_up @ X (+ b_up): KC=64, grid (64, 8), kIters=8 (8*8*64=4096)
  agg_kernel<<<dim3(N_NODES / 64, 8), 256, 0, stream>>>(
      Wupb, 64, XT, N_NODES, accb, 8);
  reduce_acc_kernel<<<N_NODES * DIM / 256, 256, 0, stream>>>(
      accb, XuNew, bup, nullptr, nullptr, 0, 8);

  // Adj blocks [[A,A],[A,.]] fp8 + colsum; deg; S0 = sigmoid(new@new^T) -> quadrant (1,1)
  cast_a_kernel<<<dim3(N_NODES / 256, N_NODES / 128), 256, 0, stream>>>(A, Adj, colsumA);
  init_deg_kernel<<<M_NODES / 256, 256, 0, stream>>>(colsumA, deg);
  rebuild_kernel<0><<<dim3(N_NODES / 128, N_NODES / 128), 256, 0, stream>>>(
      XuNew, XuNew, Adj, N_NODES, N_NODES, deg);

  for (int it = 0; it < 3; ++it) {
    // conv1
    yz_kernel<<<M_NODES / 128, 256, 0, stream>>>(Xu, W1T, deg, ZT, M_NODES);
    agg_kernel<<<dim3(M_NODES / 64, 8), 256, 0, stream>>>(
        Adj, 128, ZT, M_NODES, accb, 16);
    reduce_acc_kernel<<<M_NODES * DIM / 256, 256, 0, stream>>>(
        accb, Xu, nullptr, b1, deg, 1, 8);
    // mid-loop Adj rebuild + deg
    hipMemsetAsync(deg, 0, M_NODES * 4, stream);
    rebuild_kernel<0><<<dim3(M_NODES / 128, M_NODES / 128), 256, 0, stream>>>(
        Xu, Xu, Adj, 0, 0, deg);
    // conv2
    yz_kernel<<<M_NODES / 128, 256, 0, stream>>>(Xu, W2T, deg, ZT, M_NODES);
    agg_kernel<<<dim3(M_NODES / 64, 8), 256, 0, stream>>>(
        Adj, 128, ZT, M_NODES, accb, 16);
    reduce_acc_kernel<<<M_NODES * DIM / 256, 256, 0, stream>>>(
        accb, Xu, nullptr, b2, deg, 1, 8);
    if (it == 2)
      rebuild_kernel<1><<<dim3(M_NODES / 128, M_NODES / 128), 256, 0, stream>>>(
          Xu, Xu, d_out, M_NODES, 0, nullptr);
  }
}